// Round 22
// baseline (70.505 us; speedup 1.0000x reference)
//
#include <hip/hip_runtime.h>

#pragma clang fp contract(off)

#define N_PTS   16384
#define N_SEEDS 20
#define KP1     11      // K+1, K=10
#define NBIN    512     // bits(d2) >> 22 : exponent + 1 mantissa bit
#define NREP    32      // hist[bin*32 + (t&31)] -> bank == t&31 (conflict-free)
#define CAP     4096    // candidate buffer; also LDS pad: >80KB total -> 1 block/CU
#define NKNN    3       // knn-role blocks per batch

typedef unsigned long long u64;
typedef unsigned int       u32;

// DPP fmax step: m = fmax(m, dpp_select(m)). VALU pipe (~5cyc) vs ds_swizzle.
#define FMAXDPP(m, ctrl, rmask) { \
    const int _v = __builtin_amdgcn_update_dpp(__float_as_int(m), __float_as_int(m), \
                                               (ctrl), (rmask), 0xf, false); \
    m = fmaxf(m, __int_as_float(_v)); }

#define FDECL(i) float px##i, py##i, pz##i, dd##i = 1e10f;
#define LOADPTS(P4)                                                         \
    {   const int f4 = t * 12;                                              \
        const float4 q0 = P4[f4+0],  q1 = P4[f4+1],  q2  = P4[f4+2];        \
        const float4 q3 = P4[f4+3],  q4 = P4[f4+4],  q5  = P4[f4+5];        \
        const float4 q6 = P4[f4+6],  q7 = P4[f4+7],  q8  = P4[f4+8];        \
        const float4 q9 = P4[f4+9],  q10 = P4[f4+10], q11 = P4[f4+11];      \
        px0 =q0.x;  py0 =q0.y;  pz0 =q0.z;                                  \
        px1 =q0.w;  py1 =q1.x;  pz1 =q1.y;                                  \
        px2 =q1.z;  py2 =q1.w;  pz2 =q2.x;                                  \
        px3 =q2.y;  py3 =q2.z;  pz3 =q2.w;                                  \
        px4 =q3.x;  py4 =q3.y;  pz4 =q3.z;                                  \
        px5 =q3.w;  py5 =q4.x;  pz5 =q4.y;                                  \
        px6 =q4.z;  py6 =q4.w;  pz6 =q5.x;                                  \
        px7 =q5.y;  py7 =q5.z;  pz7 =q5.w;                                  \
        px8 =q6.x;  py8 =q6.y;  pz8 =q6.z;                                  \
        px9 =q6.w;  py9 =q7.x;  pz9 =q7.y;                                  \
        px10=q7.z;  py10=q7.w;  pz10=q8.x;                                  \
        px11=q8.y;  py11=q8.z;  pz11=q8.w;                                  \
        px12=q9.x;  py12=q9.y;  pz12=q9.z;                                  \
        px13=q9.w;  py13=q10.x; pz13=q10.y;                                 \
        px14=q10.z; py14=q10.w; pz14=q11.x;                                 \
        px15=q11.y; py15=q11.z; pz15=q11.w; }

// ---------------------------------------------------------------------------
// One kernel, three roles, all concurrent (256 blocks x 1024 thr, ~84KB LDS
// -> exactly 1 block/CU on 256 CUs -> guaranteed co-residency for spins).
//   bid <  B : FPS, SINGLE barrier/iter: indexless FSTEP (10 VALU/pt, 4
//              independent chains); wave max via DPP; each wave recovers its
//              own winner BEFORE the barrier (ballot bestv==wmax -> lowest
//              lane -> descending dd scan = first index) and publishes
//              {wmax} + {idx,coords}; after B1 every wave DPP-reduces the 16
//              wave maxima, lowest tied wave wins, one s_pack read. Exact
//              first-index semantics at all levels. RELAXED seed publish;
//              iter 19 compute skipped (argmax discarded by reference scan).
//   bid >= B : kNN radix-select (r13/r20 bitwise-frozen); RELAXED seed poll;
//              threadfence + done-add at end.
//   bid == B : polls done==NKNN*B-1 (init -1), fences, stats in-kernel.
// ---------------------------------------------------------------------------
__global__ __launch_bounds__(1024)
__attribute__((amdgpu_waves_per_eu(4, 4)))
void fused_kernel(const float* __restrict__ pcs,
                  int* __restrict__ seeds,
                  int* __restrict__ done,
                  float* __restrict__ topd,
                  float* __restrict__ out,
                  int B) {
    __shared__ alignas(16) u32 hist[NBIN * NREP];   // 64 KB (knn) / f64 scratch (stats)
    __shared__ u32    part[NBIN];
    __shared__ float  cand[CAP];                    // 16 KB (also the >80KB pad)
    __shared__ u32    cnt;
    __shared__ u32    s_thr;
    __shared__ int    s_sid;
    __shared__ float  s_val[2][16];                 // fps: wave maxima
    __shared__ float4 s_pack[2][16];                // fps: {idx_bits, cx, cy, cz}

    const int bid  = blockIdx.x;
    const int t    = threadIdx.x;
    const int lane = t & 63;
    const int wid  = t >> 6;

    if (bid < B) {
        // ================= FPS role =================
        const float* __restrict__ P  = pcs + (size_t)bid * N_PTS * 3;
        const float4* __restrict__ P4 = (const float4*)P;

        FDECL(0)  FDECL(1)  FDECL(2)  FDECL(3)
        FDECL(4)  FDECL(5)  FDECL(6)  FDECL(7)
        FDECL(8)  FDECL(9)  FDECL(10) FDECL(11)
        FDECL(12) FDECL(13) FDECL(14) FDECL(15)
        LOADPTS(P4)

        float cx = P[0], cy = P[1], cz = P[2];
        int farthest = 0;

        for (int it = 0; it < N_SEEDS; ++it) {
            if (t == 0)    // RELAXED: value-only payload (r9-proven)
                __hip_atomic_store(&seeds[bid * N_SEEDS + it], farthest,
                                   __ATOMIC_RELAXED, __HIP_MEMORY_SCOPE_AGENT);
            if (it == N_SEEDS - 1) break;   // last argmax discarded by scan

            // ---- indexless FSTEP: 4 independent value-only max chains -----
            float v0 = -1.f, v1 = -1.f, v2 = -1.f, v3 = -1.f;
#define FS(c, i) { const float dx = px##i - cx, dy = py##i - cy, dz = pz##i - cz; \
        const float d  = (dx*dx + dy*dy) + dz*dz; \
        const float nd = fminf(dd##i, d); dd##i = nd; \
        v##c = fmaxf(v##c, nd); }
            FS(0,0)  FS(1,1)  FS(2,2)  FS(3,3)
            FS(0,4)  FS(1,5)  FS(2,6)  FS(3,7)
            FS(0,8)  FS(1,9)  FS(2,10) FS(3,11)
            FS(0,12) FS(1,13) FS(2,14) FS(3,15)
            const float bestv = fmaxf(fmaxf(v0, v1), fmaxf(v2, v3));

            // ---- wave max via DPP -----------------------------------------
            float m = bestv;
            FMAXDPP(m, 0x111, 0xf)   // row_shr:1
            FMAXDPP(m, 0x112, 0xf)   // row_shr:2
            FMAXDPP(m, 0x114, 0xf)   // row_shr:4
            FMAXDPP(m, 0x118, 0xf)   // row_shr:8
            FMAXDPP(m, 0x142, 0xa)   // row_bcast:15
            FMAXDPP(m, 0x143, 0xc)   // row_bcast:31; lane63 = wave max
            const float wmax = __int_as_float(
                __builtin_amdgcn_readlane(__float_as_int(m), 63));

            // ---- per-wave winner recovery (pre-barrier, parallel) ---------
            const int par = it & 1;
            const u64 lm = __ballot(bestv == wmax);
            const int ll = __ffsll((unsigned long long)lm) - 1;
            if (lane == ll) {        // lowest lane holding the wave max
                int fi = 0; float sx = 0.f, sy = 0.f, sz = 0.f;
#define SCAN(i) if (dd##i == wmax) { fi = t*16 + (i); sx = px##i; sy = py##i; sz = pz##i; }
                SCAN(15) SCAN(14) SCAN(13) SCAN(12)
                SCAN(11) SCAN(10) SCAN(9)  SCAN(8)
                SCAN(7)  SCAN(6)  SCAN(5)  SCAN(4)
                SCAN(3)  SCAN(2)  SCAN(1)  SCAN(0)
                s_val[par][wid]  = wmax;
                s_pack[par][wid] = make_float4(__int_as_float(fi), sx, sy, sz);
            }
            __syncthreads();         // B1 (only barrier): all winners in LDS

            // ---- block max over 16 wave maxima via row-DPP ----------------
            const float v16 = s_val[par][lane & 15];
            float r = v16;
            FMAXDPP(r, 0x111, 0xf)
            FMAXDPP(r, 0x112, 0xf)
            FMAXDPP(r, 0x114, 0xf)
            FMAXDPP(r, 0x118, 0xf)   // lane15 = max of the 16
            const float gmax = __int_as_float(
                __builtin_amdgcn_readlane(__float_as_int(r), 15));
            const u64 m2 = __ballot(v16 == gmax) & 0xFFFFull;
            const int ws = __ffsll((unsigned long long)m2) - 1;
            const float4 pk = s_pack[par][ws];   // one b128 broadcast read
            farthest = __float_as_int(pk.x);
            cx = pk.y; cy = pk.z; cz = pk.w;
        }
    } else {
        // ================= kNN-select role (r13/r20 bitwise-frozen) ========
        const int kk = bid - B;
        const int b  = kk % B;          // bid ≡ b (mod 8): same XCD as fps block
        const int j  = kk / B;

        const float* __restrict__ P  = pcs + (size_t)b * N_PTS * 3;
        const float4* __restrict__ P4 = (const float4*)P;
        const int rep = t & 31;

        FDECL(0)  FDECL(1)  FDECL(2)  FDECL(3)
        FDECL(4)  FDECL(5)  FDECL(6)  FDECL(7)
        FDECL(8)  FDECL(9)  FDECL(10) FDECL(11)
        FDECL(12) FDECL(13) FDECL(14) FDECL(15)
        LOADPTS(P4)        // dd regs unused -> DCE'd

#pragma unroll
        for (int i = 0; i < (NBIN * NREP) / 1024; ++i) hist[t + i * 1024] = 0u;
        if (t == 0) cnt = 0u;

        for (int s = j; s < N_SEEDS; s += NKNN) {
            if (t == 0) {   // RELAXED poll: seed index is the whole payload
                int sv;
                while ((sv = __hip_atomic_load(&seeds[b * N_SEEDS + s],
                               __ATOMIC_RELAXED, __HIP_MEMORY_SCOPE_AGENT)) < 0)
                    __builtin_amdgcn_s_sleep(2);
                s_sid = sv;
            }
            __syncthreads();                  // B0: sid ready, hist+cnt zeroed
            const int sid = s_sid;
            const float cx = P[sid*3], cy = P[sid*3+1], cz = P[sid*3+2];

            // ---- histogram pass (d transient) -----------------------------
#define HSTEP(i) { const float dx = px##i - cx, dy = py##i - cy, dz = pz##i - cz; \
        const float d = fmaf(dz, dz, fmaf(dy, dy, dx * dx)); \
        atomicAdd(&hist[(__float_as_uint(d) >> 22) * NREP + rep], 1u); }
            HSTEP(0)  HSTEP(1)  HSTEP(2)  HSTEP(3)
            HSTEP(4)  HSTEP(5)  HSTEP(6)  HSTEP(7)
            HSTEP(8)  HSTEP(9)  HSTEP(10) HSTEP(11)
            HSTEP(12) HSTEP(13) HSTEP(14) HSTEP(15)
            __syncthreads();                  // B1: hist complete

            if (t < NBIN) {
                u32 ssum = 0;
#pragma unroll
                for (int r2 = 0; r2 < NREP; ++r2)
                    ssum += hist[t * NREP + ((r2 + t) & (NREP - 1))];
                part[t] = ssum;
            }
            __syncthreads();                  // B2: part[] ready

            if (wid == 0) {
                u32 s8 = 0;
#pragma unroll
                for (int i = 0; i < 8; ++i)
                    s8 += part[lane * 8 + ((i + lane) & 7)];
                u32 cum = s8;
                for (int off = 1; off < 64; off <<= 1) {
                    const u32 o = __shfl_up(cum, off);
                    if (lane >= off) cum += o;
                }
                const u64 mm = __ballot(cum >= (u32)KP1);
                const int L  = __ffsll((unsigned long long)mm) - 1;
                const u32 below = __shfl(cum - s8, L);
                const u32 bc = (lane < 8) ? part[L * 8 + lane] : 0u;
                u32 ic = bc;
                for (int off = 1; off < 8; off <<= 1) {
                    const u32 o = __shfl_up(ic, off);
                    if (lane >= off) ic += o;
                }
                const u64 mm2 = __ballot(lane < 8 && (below + ic) >= (u32)KP1);
                const int l2  = __ffsll((unsigned long long)mm2) - 1;
                if (lane == 0) s_thr = (u32)(L * 8 + l2 + 1) << 22;
            } else {
                if (t == 64) cnt = 0u;        // reset for this seed's collect
                for (int i = t - 64; i < NBIN * NREP; i += 960) hist[i] = 0u;
            }
            __syncthreads();                  // B3: thr ready, hist zeroed, cnt=0

            // ---- collect candidates (recompute d: bitwise same as HSTEP) --
            const float thrf = __uint_as_float(s_thr);
#define CSTEP(i) { const float dx = px##i - cx, dy = py##i - cy, dz = pz##i - cz; \
        const float d = fmaf(dz, dz, fmaf(dy, dy, dx * dx)); \
        if (d < thrf) { const u32 sl = atomicAdd(&cnt, 1u); \
                        if (sl < (u32)CAP) cand[sl] = d; } }
            CSTEP(0)  CSTEP(1)  CSTEP(2)  CSTEP(3)
            CSTEP(4)  CSTEP(5)  CSTEP(6)  CSTEP(7)
            CSTEP(8)  CSTEP(9)  CSTEP(10) CSTEP(11)
            CSTEP(12) CSTEP(13) CSTEP(14) CSTEP(15)
            __syncthreads();                  // B4: candidates ready

            if (wid == 0) {
                const u32 n = min(cnt, (u32)CAP);
                for (u32 base = 0; base < n; base += 64) {
                    const u32 idx = base + (u32)lane;
                    const float vv = (idx < n) ? cand[idx] : 3.0e38f;
                    u32 r2 = 0;
                    for (u32 jj = 0; jj < n; ++jj) {
                        const float w = cand[jj];
                        r2 += (w < vv || (w == vv && jj < idx)) ? 1u : 0u;
                    }
                    if (idx < n && r2 < (u32)KP1)
                        topd[(b * N_SEEDS + s) * KP1 + r2] = sqrtf(vv);
                }
            }
        }

        // -------- signal completion (one fence per block, off hot path) ----
        __syncthreads();
        if (t == 0) {
            __threadfence();                  // make topd visible at agent scope
            __hip_atomic_fetch_add(done, 1, __ATOMIC_RELAXED,
                                   __HIP_MEMORY_SCOPE_AGENT);
        }

        // ================= stats role (block B only) =======================
        if (bid == B) {
            const int target = NKNN * B - 1;      // done init = -1 (0xFF memset)
            if (t == 0) {
                while (__hip_atomic_load(done, __ATOMIC_RELAXED,
                                         __HIP_MEMORY_SCOPE_AGENT) != target)
                    __builtin_amdgcn_s_sleep(8);
            }
            __syncthreads();
            __threadfence();    // acquire side: invalidate before topd reads

            const int pairs = B * N_SEEDS;
            const int total = pairs * KP1;
            double* red = (double*)hist;          // 8 KB scratch, hist is dead

            double s1 = 0.0;
            for (int i = t; i < total; i += 1024)
                if (i % KP1 != 0) s1 += (double)topd[i];
            red[t] = s1;
            __syncthreads();
            for (int off = 512; off; off >>= 1) {
                if (t < off) red[t] += red[t + off];
                __syncthreads();
            }
            const double om = red[0] / (double)(pairs * (KP1 - 1));

            double sm = 0.0, sm2 = 0.0;
            for (int pr = t; pr < pairs; pr += 1024) {
                double acc = 0.0;
                for (int jj = 0; jj < KP1; ++jj) acc += (double)topd[pr * KP1 + jj];
                const double m = acc / (om * (double)KP1);
                sm += m;
                sm2 += m * m;
            }
            __syncthreads();
            red[t] = sm;
            __syncthreads();
            for (int off = 512; off; off >>= 1) {
                if (t < off) red[t] += red[t + off];
                __syncthreads();
            }
            const double Sm = red[0];
            __syncthreads();
            red[t] = sm2;
            __syncthreads();
            for (int off = 512; off; off >>= 1) {
                if (t < off) red[t] += red[t + off];
                __syncthreads();
            }
            if (t == 0) {
                const double var = (red[0] - Sm * Sm / (double)pairs)
                                   / (double)(pairs - 1);
                out[0] = (float)var;
            }
        }
    }
}

// ---------------------------------------------------------------------------
extern "C" void kernel_launch(void* const* d_in, const int* in_sizes, int n_in,
                              void* d_out, int out_size, void* d_ws, size_t ws_size,
                              hipStream_t stream) {
    const float* pcs = (const float*)d_in[0];
    const int B = in_sizes[0] / (N_PTS * 3);

    int*   seeds = (int*)d_ws;                          // B*20 ints
    int*   done  = (int*)((char*)d_ws + 5120);          // 1 int, init -1
    float* topd  = (float*)((char*)d_ws + 8192);        // B*20*11 floats
    float* out   = (float*)d_out;

    // seeds -> -1, done -> -1 every launch (graph replays don't re-poison)
    (void)hipMemsetAsync(d_ws, 0xFF, 8192, stream);

    fused_kernel<<<B * (1 + NKNN), 1024, 0, stream>>>(pcs, seeds, done, topd, out, B);
}

// Round 23
// 56.239 us; speedup vs baseline: 1.2537x; 1.2537x over previous
//
#include <hip/hip_runtime.h>

#pragma clang fp contract(off)

#define N_PTS   16384
#define N_SEEDS 20
#define KP1     11      // K+1, K=10
#define NBIN    512     // bits(d2) >> 22 : exponent + 1 mantissa bit
#define NREP    32      // hist[bin*32 + (t&31)] -> bank == t&31 (conflict-free)
#define CAP     4096    // candidate buffer; also LDS pad: >80KB total -> 1 block/CU
#define NKNN    3       // knn-role blocks per batch

typedef unsigned long long u64;
typedef unsigned int       u32;

// DPP fmax step: m = fmax(m, dpp_select(m)). VALU pipe (~5cyc) vs ds_swizzle.
#define FMAXDPP(m, ctrl, rmask) { \
    const int _v = __builtin_amdgcn_update_dpp(__float_as_int(m), __float_as_int(m), \
                                               (ctrl), (rmask), 0xf, false); \
    m = fmaxf(m, __int_as_float(_v)); }

#define FDECL(i) float px##i, py##i, pz##i, dd##i = 1e10f;
#define LOADPTS(P4)                                                         \
    {   const int f4 = t * 12;                                              \
        const float4 q0 = P4[f4+0],  q1 = P4[f4+1],  q2  = P4[f4+2];        \
        const float4 q3 = P4[f4+3],  q4 = P4[f4+4],  q5  = P4[f4+5];        \
        const float4 q6 = P4[f4+6],  q7 = P4[f4+7],  q8  = P4[f4+8];        \
        const float4 q9 = P4[f4+9],  q10 = P4[f4+10], q11 = P4[f4+11];      \
        px0 =q0.x;  py0 =q0.y;  pz0 =q0.z;                                  \
        px1 =q0.w;  py1 =q1.x;  pz1 =q1.y;                                  \
        px2 =q1.z;  py2 =q1.w;  pz2 =q2.x;                                  \
        px3 =q2.y;  py3 =q2.z;  pz3 =q2.w;                                  \
        px4 =q3.x;  py4 =q3.y;  pz4 =q3.z;                                  \
        px5 =q3.w;  py5 =q4.x;  pz5 =q4.y;                                  \
        px6 =q4.z;  py6 =q4.w;  pz6 =q5.x;                                  \
        px7 =q5.y;  py7 =q5.z;  pz7 =q5.w;                                  \
        px8 =q6.x;  py8 =q6.y;  pz8 =q6.z;                                  \
        px9 =q6.w;  py9 =q7.x;  pz9 =q7.y;                                  \
        px10=q7.z;  py10=q7.w;  pz10=q8.x;                                  \
        px11=q8.y;  py11=q8.z;  pz11=q8.w;                                  \
        px12=q9.x;  py12=q9.y;  pz12=q9.z;                                  \
        px13=q9.w;  py13=q10.x; pz13=q10.y;                                 \
        px14=q10.z; py14=q10.w; pz14=q11.x;                                 \
        px15=q11.y; py15=q11.z; pz15=q11.w; }

// ---------------------------------------------------------------------------
// One kernel, three roles, all concurrent (256 blocks x 1024 thr, ~84KB LDS
// -> exactly 1 block/CU on 256 CUs -> guaranteed co-residency for spins).
//   bid <  B : FPS. FSTEP is INDEXLESS (10 VALU/pt: dist + fmin + fmax into
//              4 independent chains) - the argmax identity is recovered after
//              the block max is known: lowest wave w/ wmax==gmax (ballot/16),
//              lowest lane w/ bestv==gmax (ballot/64), descending dd scan on
//              that single lane -> first index. Exact first-index semantics
//              (fmax is bit-exact, so == matches are precise; lane/wave order
//              == index order). 2 barriers/iter. RELAXED seed publish; iter
//              19 compute skipped (argmax discarded by reference scan).
//   bid >= B : kNN radix-select (r13 bitwise-frozen); RELAXED seed poll;
//              threadfence + done-add at end.
//   bid == B : polls done==NKNN*B-1 (init -1), fences, stats in-kernel.
// ---------------------------------------------------------------------------
__global__ __launch_bounds__(1024)
__attribute__((amdgpu_waves_per_eu(4, 4)))
void fused_kernel(const float* __restrict__ pcs,
                  int* __restrict__ seeds,
                  int* __restrict__ done,
                  float* __restrict__ topd,
                  float* __restrict__ out,
                  int B) {
    __shared__ alignas(16) u32 hist[NBIN * NREP];   // 64 KB (knn) / f64 scratch (stats)
    __shared__ u32    part[NBIN];
    __shared__ float  cand[CAP];                    // 16 KB (also the >80KB pad)
    __shared__ u32    cnt;
    __shared__ u32    s_thr;
    __shared__ int    s_sid;
    __shared__ float  s_val[2][16];                 // fps: wave maxima
    __shared__ float4 s_pack[2];                    // fps: {idx_bits, cx, cy, cz}

    const int bid  = blockIdx.x;
    const int t    = threadIdx.x;
    const int lane = t & 63;
    const int wid  = t >> 6;

    if (bid < B) {
        // ================= FPS role =================
        const float* __restrict__ P  = pcs + (size_t)bid * N_PTS * 3;
        const float4* __restrict__ P4 = (const float4*)P;

        FDECL(0)  FDECL(1)  FDECL(2)  FDECL(3)
        FDECL(4)  FDECL(5)  FDECL(6)  FDECL(7)
        FDECL(8)  FDECL(9)  FDECL(10) FDECL(11)
        FDECL(12) FDECL(13) FDECL(14) FDECL(15)
        LOADPTS(P4)

        float cx = P[0], cy = P[1], cz = P[2];
        int farthest = 0;

        for (int it = 0; it < N_SEEDS; ++it) {
            if (t == 0)    // RELAXED: value-only payload (r9-proven)
                __hip_atomic_store(&seeds[bid * N_SEEDS + it], farthest,
                                   __ATOMIC_RELAXED, __HIP_MEMORY_SCOPE_AGENT);
            if (it == N_SEEDS - 1) break;   // last argmax discarded by scan

            // ---- indexless FSTEP: 4 independent value-only max chains -----
            float v0 = -1.f, v1 = -1.f, v2 = -1.f, v3 = -1.f;
#define FS(c, i) { const float dx = px##i - cx, dy = py##i - cy, dz = pz##i - cz; \
        const float d  = (dx*dx + dy*dy) + dz*dz; \
        const float nd = fminf(dd##i, d); dd##i = nd; \
        v##c = fmaxf(v##c, nd); }
            FS(0,0)  FS(1,1)  FS(2,2)  FS(3,3)
            FS(0,4)  FS(1,5)  FS(2,6)  FS(3,7)
            FS(0,8)  FS(1,9)  FS(2,10) FS(3,11)
            FS(0,12) FS(1,13) FS(2,14) FS(3,15)
            const float bestv = fmaxf(fmaxf(v0, v1), fmaxf(v2, v3));

            // ---- stage 1: wave max via DPP (no index tracking) ------------
            float m = bestv;
            FMAXDPP(m, 0x111, 0xf)   // row_shr:1
            FMAXDPP(m, 0x112, 0xf)   // row_shr:2
            FMAXDPP(m, 0x114, 0xf)   // row_shr:4
            FMAXDPP(m, 0x118, 0xf)   // row_shr:8
            FMAXDPP(m, 0x142, 0xa)   // row_bcast:15
            FMAXDPP(m, 0x143, 0xc)   // row_bcast:31; lane63 = wave max
            const float wmax = __int_as_float(
                __builtin_amdgcn_readlane(__float_as_int(m), 63));
            const int par = it & 1;
            if (lane == 0) s_val[par][wid] = wmax;
            __syncthreads();                 // B1: all wave maxima in LDS

            // ---- stage 2: block max; winner wave/lane recovers the index --
            const float v16 = s_val[par][lane & 15];
            float r = v16;
            FMAXDPP(r, 0x111, 0xf)
            FMAXDPP(r, 0x112, 0xf)
            FMAXDPP(r, 0x114, 0xf)
            FMAXDPP(r, 0x118, 0xf)   // lane15 = max of the 16
            const float gmax = __int_as_float(
                __builtin_amdgcn_readlane(__float_as_int(r), 15));
            const u64 m2 = __ballot(v16 == gmax) & 0xFFFFull;
            const int ws = __ffsll((unsigned long long)m2) - 1;

            if (wid == ws) {                 // winning wave only
                const u64 lm = __ballot(bestv == gmax);
                const int ll = __ffsll((unsigned long long)lm) - 1;
                if (lane == ll) {            // winning lane: descending scan
                    int fi = 0; float sx = 0.f, sy = 0.f, sz = 0.f;
#define SCAN(i) if (dd##i == gmax) { fi = t*16 + (i); sx = px##i; sy = py##i; sz = pz##i; }
                    SCAN(15) SCAN(14) SCAN(13) SCAN(12)
                    SCAN(11) SCAN(10) SCAN(9)  SCAN(8)
                    SCAN(7)  SCAN(6)  SCAN(5)  SCAN(4)
                    SCAN(3)  SCAN(2)  SCAN(1)  SCAN(0)
                    s_pack[par] = make_float4(__int_as_float(fi), sx, sy, sz);
                }
            }
            __syncthreads();                 // B2: winner published

            const float4 pk = s_pack[par];
            farthest = __float_as_int(pk.x);
            cx = pk.y; cy = pk.z; cz = pk.w;
        }
    } else {
        // ================= kNN-select role (r13 bitwise-frozen) ============
        const int kk = bid - B;
        const int b  = kk % B;          // bid ≡ b (mod 8): same XCD as fps block
        const int j  = kk / B;

        const float* __restrict__ P  = pcs + (size_t)b * N_PTS * 3;
        const float4* __restrict__ P4 = (const float4*)P;
        const int rep = t & 31;

        FDECL(0)  FDECL(1)  FDECL(2)  FDECL(3)
        FDECL(4)  FDECL(5)  FDECL(6)  FDECL(7)
        FDECL(8)  FDECL(9)  FDECL(10) FDECL(11)
        FDECL(12) FDECL(13) FDECL(14) FDECL(15)
        LOADPTS(P4)        // dd regs unused -> DCE'd

#pragma unroll
        for (int i = 0; i < (NBIN * NREP) / 1024; ++i) hist[t + i * 1024] = 0u;
        if (t == 0) cnt = 0u;

        for (int s = j; s < N_SEEDS; s += NKNN) {
            if (t == 0) {   // RELAXED poll: seed index is the whole payload
                int sv;
                while ((sv = __hip_atomic_load(&seeds[b * N_SEEDS + s],
                               __ATOMIC_RELAXED, __HIP_MEMORY_SCOPE_AGENT)) < 0)
                    __builtin_amdgcn_s_sleep(2);
                s_sid = sv;
            }
            __syncthreads();                  // B0: sid ready, hist+cnt zeroed
            const int sid = s_sid;
            const float cx = P[sid*3], cy = P[sid*3+1], cz = P[sid*3+2];

            // ---- histogram pass (d transient) -----------------------------
#define HSTEP(i) { const float dx = px##i - cx, dy = py##i - cy, dz = pz##i - cz; \
        const float d = fmaf(dz, dz, fmaf(dy, dy, dx * dx)); \
        atomicAdd(&hist[(__float_as_uint(d) >> 22) * NREP + rep], 1u); }
            HSTEP(0)  HSTEP(1)  HSTEP(2)  HSTEP(3)
            HSTEP(4)  HSTEP(5)  HSTEP(6)  HSTEP(7)
            HSTEP(8)  HSTEP(9)  HSTEP(10) HSTEP(11)
            HSTEP(12) HSTEP(13) HSTEP(14) HSTEP(15)
            __syncthreads();                  // B1: hist complete

            if (t < NBIN) {
                u32 ssum = 0;
#pragma unroll
                for (int r2 = 0; r2 < NREP; ++r2)
                    ssum += hist[t * NREP + ((r2 + t) & (NREP - 1))];
                part[t] = ssum;
            }
            __syncthreads();                  // B2: part[] ready

            if (wid == 0) {
                u32 s8 = 0;
#pragma unroll
                for (int i = 0; i < 8; ++i)
                    s8 += part[lane * 8 + ((i + lane) & 7)];
                u32 cum = s8;
                for (int off = 1; off < 64; off <<= 1) {
                    const u32 o = __shfl_up(cum, off);
                    if (lane >= off) cum += o;
                }
                const u64 mm = __ballot(cum >= (u32)KP1);
                const int L  = __ffsll((unsigned long long)mm) - 1;
                const u32 below = __shfl(cum - s8, L);
                const u32 bc = (lane < 8) ? part[L * 8 + lane] : 0u;
                u32 ic = bc;
                for (int off = 1; off < 8; off <<= 1) {
                    const u32 o = __shfl_up(ic, off);
                    if (lane >= off) ic += o;
                }
                const u64 mm2 = __ballot(lane < 8 && (below + ic) >= (u32)KP1);
                const int l2  = __ffsll((unsigned long long)mm2) - 1;
                if (lane == 0) s_thr = (u32)(L * 8 + l2 + 1) << 22;
            } else {
                if (t == 64) cnt = 0u;        // reset for this seed's collect
                for (int i = t - 64; i < NBIN * NREP; i += 960) hist[i] = 0u;
            }
            __syncthreads();                  // B3: thr ready, hist zeroed, cnt=0

            // ---- collect candidates (recompute d: bitwise same as HSTEP) --
            const float thrf = __uint_as_float(s_thr);
#define CSTEP(i) { const float dx = px##i - cx, dy = py##i - cy, dz = pz##i - cz; \
        const float d = fmaf(dz, dz, fmaf(dy, dy, dx * dx)); \
        if (d < thrf) { const u32 sl = atomicAdd(&cnt, 1u); \
                        if (sl < (u32)CAP) cand[sl] = d; } }
            CSTEP(0)  CSTEP(1)  CSTEP(2)  CSTEP(3)
            CSTEP(4)  CSTEP(5)  CSTEP(6)  CSTEP(7)
            CSTEP(8)  CSTEP(9)  CSTEP(10) CSTEP(11)
            CSTEP(12) CSTEP(13) CSTEP(14) CSTEP(15)
            __syncthreads();                  // B4: candidates ready

            if (wid == 0) {
                const u32 n = min(cnt, (u32)CAP);
                for (u32 base = 0; base < n; base += 64) {
                    const u32 idx = base + (u32)lane;
                    const float vv = (idx < n) ? cand[idx] : 3.0e38f;
                    u32 r2 = 0;
                    for (u32 jj = 0; jj < n; ++jj) {
                        const float w = cand[jj];
                        r2 += (w < vv || (w == vv && jj < idx)) ? 1u : 0u;
                    }
                    if (idx < n && r2 < (u32)KP1)
                        topd[(b * N_SEEDS + s) * KP1 + r2] = sqrtf(vv);
                }
            }
        }

        // -------- signal completion (one fence per block, off hot path) ----
        __syncthreads();
        if (t == 0) {
            __threadfence();                  // make topd visible at agent scope
            __hip_atomic_fetch_add(done, 1, __ATOMIC_RELAXED,
                                   __HIP_MEMORY_SCOPE_AGENT);
        }

        // ================= stats role (block B only) =======================
        if (bid == B) {
            const int target = NKNN * B - 1;      // done init = -1 (0xFF memset)
            if (t == 0) {
                while (__hip_atomic_load(done, __ATOMIC_RELAXED,
                                         __HIP_MEMORY_SCOPE_AGENT) != target)
                    __builtin_amdgcn_s_sleep(8);
            }
            __syncthreads();
            __threadfence();    // acquire side: invalidate before topd reads

            const int pairs = B * N_SEEDS;
            const int total = pairs * KP1;
            double* red = (double*)hist;          // 8 KB scratch, hist is dead

            double s1 = 0.0;
            for (int i = t; i < total; i += 1024)
                if (i % KP1 != 0) s1 += (double)topd[i];
            red[t] = s1;
            __syncthreads();
            for (int off = 512; off; off >>= 1) {
                if (t < off) red[t] += red[t + off];
                __syncthreads();
            }
            const double om = red[0] / (double)(pairs * (KP1 - 1));

            double sm = 0.0, sm2 = 0.0;
            for (int pr = t; pr < pairs; pr += 1024) {
                double acc = 0.0;
                for (int jj = 0; jj < KP1; ++jj) acc += (double)topd[pr * KP1 + jj];
                const double m = acc / (om * (double)KP1);
                sm += m;
                sm2 += m * m;
            }
            __syncthreads();
            red[t] = sm;
            __syncthreads();
            for (int off = 512; off; off >>= 1) {
                if (t < off) red[t] += red[t + off];
                __syncthreads();
            }
            const double Sm = red[0];
            __syncthreads();
            red[t] = sm2;
            __syncthreads();
            for (int off = 512; off; off >>= 1) {
                if (t < off) red[t] += red[t + off];
                __syncthreads();
            }
            if (t == 0) {
                const double var = (red[0] - Sm * Sm / (double)pairs)
                                   / (double)(pairs - 1);
                out[0] = (float)var;
            }
        }
    }
}

// ---------------------------------------------------------------------------
extern "C" void kernel_launch(void* const* d_in, const int* in_sizes, int n_in,
                              void* d_out, int out_size, void* d_ws, size_t ws_size,
                              hipStream_t stream) {
    const float* pcs = (const float*)d_in[0];
    const int B = in_sizes[0] / (N_PTS * 3);

    int*   seeds = (int*)d_ws;                          // B*20 ints
    int*   done  = (int*)((char*)d_ws + 5120);          // 1 int, init -1
    float* topd  = (float*)((char*)d_ws + 8192);        // B*20*11 floats
    float* out   = (float*)d_out;

    // seeds -> -1, done -> -1 every launch (graph replays don't re-poison)
    (void)hipMemsetAsync(d_ws, 0xFF, 8192, stream);

    fused_kernel<<<B * (1 + NKNN), 1024, 0, stream>>>(pcs, seeds, done, topd, out, B);
}

// Round 24
// 50.424 us; speedup vs baseline: 1.3982x; 1.1153x over previous
//
#include <hip/hip_runtime.h>

#pragma clang fp contract(off)

#define N_PTS   16384
#define N_SEEDS 20
#define KP1     11      // K+1, K=10
#define NBIN    512     // bits(d2) >> 22 : exponent + 1 mantissa bit
#define NREP    32      // hist[bin*32 + (t&31)] -> bank == t&31 (conflict-free)
#define CAP     4096    // candidate buffer; also LDS pad: >80KB total -> 1 block/CU
#define NKNN    3       // knn-role blocks per batch

typedef unsigned long long u64;
typedef unsigned int       u32;

// DPP fmax step: m = fmax(m, dpp_select(m)). VALU pipe (~5cyc) vs ds_swizzle.
#define FMAXDPP(m, ctrl, rmask) { \
    const int _v = __builtin_amdgcn_update_dpp(__float_as_int(m), __float_as_int(m), \
                                               (ctrl), (rmask), 0xf, false); \
    m = fmaxf(m, __int_as_float(_v)); }

#define FDECL(i) float px##i, py##i, pz##i, dd##i = 1e10f;
#define LOADPTS(P4)                                                         \
    {   const int f4 = t * 12;                                              \
        const float4 q0 = P4[f4+0],  q1 = P4[f4+1],  q2  = P4[f4+2];        \
        const float4 q3 = P4[f4+3],  q4 = P4[f4+4],  q5  = P4[f4+5];        \
        const float4 q6 = P4[f4+6],  q7 = P4[f4+7],  q8  = P4[f4+8];        \
        const float4 q9 = P4[f4+9],  q10 = P4[f4+10], q11 = P4[f4+11];      \
        px0 =q0.x;  py0 =q0.y;  pz0 =q0.z;                                  \
        px1 =q0.w;  py1 =q1.x;  pz1 =q1.y;                                  \
        px2 =q1.z;  py2 =q1.w;  pz2 =q2.x;                                  \
        px3 =q2.y;  py3 =q2.z;  pz3 =q2.w;                                  \
        px4 =q3.x;  py4 =q3.y;  pz4 =q3.z;                                  \
        px5 =q3.w;  py5 =q4.x;  pz5 =q4.y;                                  \
        px6 =q4.z;  py6 =q4.w;  pz6 =q5.x;                                  \
        px7 =q5.y;  py7 =q5.z;  pz7 =q5.w;                                  \
        px8 =q6.x;  py8 =q6.y;  pz8 =q6.z;                                  \
        px9 =q6.w;  py9 =q7.x;  pz9 =q7.y;                                  \
        px10=q7.z;  py10=q7.w;  pz10=q8.x;                                  \
        px11=q8.y;  py11=q8.z;  pz11=q8.w;                                  \
        px12=q9.x;  py12=q9.y;  pz12=q9.z;                                  \
        px13=q9.w;  py13=q10.x; pz13=q10.y;                                 \
        px14=q10.z; py14=q10.w; pz14=q11.x;                                 \
        px15=q11.y; py15=q11.z; pz15=q11.w; }

// ---------------------------------------------------------------------------
// One kernel, three roles, all concurrent (256 blocks x 1024 thr, ~84KB LDS
// -> exactly 1 block/CU on 256 CUs -> guaranteed co-residency for spins).
//   bid <  B : FPS (r20/r23 bitwise-frozen): indexless FSTEP, DPP reduce,
//              post-hoc first-index recovery, 2 barriers/iter; RELAXED seed
//              publish; iter 19 compute skipped.
//   bid >= B : kNN radix-select (bitwise-frozen); RELAXED seed poll;
//              threadfence + done-add at end.
//   bid == B : polls done==NKNN*B-1 (init -1), fences, SINGLE-PASS stats:
//              one pass over pairs -> {P=sum pairsum, Q=sum pairsum^2,
//              F=sum first-elem}; S1 = P-F; one 3-wide tree reduction
//              (11 barriers vs 31); closed-form var (r18-verified exact).
// ---------------------------------------------------------------------------
__global__ __launch_bounds__(1024)
__attribute__((amdgpu_waves_per_eu(4, 4)))
void fused_kernel(const float* __restrict__ pcs,
                  int* __restrict__ seeds,
                  int* __restrict__ done,
                  float* __restrict__ topd,
                  float* __restrict__ out,
                  int B) {
    __shared__ alignas(16) u32 hist[NBIN * NREP];   // 64 KB (knn) / f64 scratch (stats)
    __shared__ u32    part[NBIN];
    __shared__ float  cand[CAP];                    // 16 KB (also the >80KB pad)
    __shared__ u32    cnt;
    __shared__ u32    s_thr;
    __shared__ int    s_sid;
    __shared__ float  s_val[2][16];                 // fps: wave maxima
    __shared__ float4 s_pack[2];                    // fps: {idx_bits, cx, cy, cz}

    const int bid  = blockIdx.x;
    const int t    = threadIdx.x;
    const int lane = t & 63;
    const int wid  = t >> 6;

    if (bid < B) {
        // ================= FPS role =================
        const float* __restrict__ P  = pcs + (size_t)bid * N_PTS * 3;
        const float4* __restrict__ P4 = (const float4*)P;

        FDECL(0)  FDECL(1)  FDECL(2)  FDECL(3)
        FDECL(4)  FDECL(5)  FDECL(6)  FDECL(7)
        FDECL(8)  FDECL(9)  FDECL(10) FDECL(11)
        FDECL(12) FDECL(13) FDECL(14) FDECL(15)
        LOADPTS(P4)

        float cx = P[0], cy = P[1], cz = P[2];
        int farthest = 0;

        for (int it = 0; it < N_SEEDS; ++it) {
            if (t == 0)    // RELAXED: value-only payload (r9-proven)
                __hip_atomic_store(&seeds[bid * N_SEEDS + it], farthest,
                                   __ATOMIC_RELAXED, __HIP_MEMORY_SCOPE_AGENT);
            if (it == N_SEEDS - 1) break;   // last argmax discarded by scan

            // ---- indexless FSTEP: 4 independent value-only max chains -----
            float v0 = -1.f, v1 = -1.f, v2 = -1.f, v3 = -1.f;
#define FS(c, i) { const float dx = px##i - cx, dy = py##i - cy, dz = pz##i - cz; \
        const float d  = (dx*dx + dy*dy) + dz*dz; \
        const float nd = fminf(dd##i, d); dd##i = nd; \
        v##c = fmaxf(v##c, nd); }
            FS(0,0)  FS(1,1)  FS(2,2)  FS(3,3)
            FS(0,4)  FS(1,5)  FS(2,6)  FS(3,7)
            FS(0,8)  FS(1,9)  FS(2,10) FS(3,11)
            FS(0,12) FS(1,13) FS(2,14) FS(3,15)
            const float bestv = fmaxf(fmaxf(v0, v1), fmaxf(v2, v3));

            // ---- stage 1: wave max via DPP (no index tracking) ------------
            float m = bestv;
            FMAXDPP(m, 0x111, 0xf)   // row_shr:1
            FMAXDPP(m, 0x112, 0xf)   // row_shr:2
            FMAXDPP(m, 0x114, 0xf)   // row_shr:4
            FMAXDPP(m, 0x118, 0xf)   // row_shr:8
            FMAXDPP(m, 0x142, 0xa)   // row_bcast:15
            FMAXDPP(m, 0x143, 0xc)   // row_bcast:31; lane63 = wave max
            const float wmax = __int_as_float(
                __builtin_amdgcn_readlane(__float_as_int(m), 63));
            const int par = it & 1;
            if (lane == 0) s_val[par][wid] = wmax;
            __syncthreads();                 // B1: all wave maxima in LDS

            // ---- stage 2: block max; winner wave/lane recovers the index --
            const float v16 = s_val[par][lane & 15];
            float r = v16;
            FMAXDPP(r, 0x111, 0xf)
            FMAXDPP(r, 0x112, 0xf)
            FMAXDPP(r, 0x114, 0xf)
            FMAXDPP(r, 0x118, 0xf)   // lane15 = max of the 16
            const float gmax = __int_as_float(
                __builtin_amdgcn_readlane(__float_as_int(r), 15));
            const u64 m2 = __ballot(v16 == gmax) & 0xFFFFull;
            const int ws = __ffsll((unsigned long long)m2) - 1;

            if (wid == ws) {                 // winning wave only
                const u64 lm = __ballot(bestv == gmax);
                const int ll = __ffsll((unsigned long long)lm) - 1;
                if (lane == ll) {            // winning lane: descending scan
                    int fi = 0; float sx = 0.f, sy = 0.f, sz = 0.f;
#define SCAN(i) if (dd##i == gmax) { fi = t*16 + (i); sx = px##i; sy = py##i; sz = pz##i; }
                    SCAN(15) SCAN(14) SCAN(13) SCAN(12)
                    SCAN(11) SCAN(10) SCAN(9)  SCAN(8)
                    SCAN(7)  SCAN(6)  SCAN(5)  SCAN(4)
                    SCAN(3)  SCAN(2)  SCAN(1)  SCAN(0)
                    s_pack[par] = make_float4(__int_as_float(fi), sx, sy, sz);
                }
            }
            __syncthreads();                 // B2: winner published

            const float4 pk = s_pack[par];
            farthest = __float_as_int(pk.x);
            cx = pk.y; cy = pk.z; cz = pk.w;
        }
    } else {
        // ================= kNN-select role (bitwise-frozen) ================
        const int kk = bid - B;
        const int b  = kk % B;          // bid ≡ b (mod 8): same XCD as fps block
        const int j  = kk / B;

        const float* __restrict__ P  = pcs + (size_t)b * N_PTS * 3;
        const float4* __restrict__ P4 = (const float4*)P;
        const int rep = t & 31;

        FDECL(0)  FDECL(1)  FDECL(2)  FDECL(3)
        FDECL(4)  FDECL(5)  FDECL(6)  FDECL(7)
        FDECL(8)  FDECL(9)  FDECL(10) FDECL(11)
        FDECL(12) FDECL(13) FDECL(14) FDECL(15)
        LOADPTS(P4)        // dd regs unused -> DCE'd

#pragma unroll
        for (int i = 0; i < (NBIN * NREP) / 1024; ++i) hist[t + i * 1024] = 0u;
        if (t == 0) cnt = 0u;

        for (int s = j; s < N_SEEDS; s += NKNN) {
            if (t == 0) {   // RELAXED poll: seed index is the whole payload
                int sv;
                while ((sv = __hip_atomic_load(&seeds[b * N_SEEDS + s],
                               __ATOMIC_RELAXED, __HIP_MEMORY_SCOPE_AGENT)) < 0)
                    __builtin_amdgcn_s_sleep(2);
                s_sid = sv;
            }
            __syncthreads();                  // B0: sid ready, hist+cnt zeroed
            const int sid = s_sid;
            const float cx = P[sid*3], cy = P[sid*3+1], cz = P[sid*3+2];

            // ---- histogram pass (d transient) -----------------------------
#define HSTEP(i) { const float dx = px##i - cx, dy = py##i - cy, dz = pz##i - cz; \
        const float d = fmaf(dz, dz, fmaf(dy, dy, dx * dx)); \
        atomicAdd(&hist[(__float_as_uint(d) >> 22) * NREP + rep], 1u); }
            HSTEP(0)  HSTEP(1)  HSTEP(2)  HSTEP(3)
            HSTEP(4)  HSTEP(5)  HSTEP(6)  HSTEP(7)
            HSTEP(8)  HSTEP(9)  HSTEP(10) HSTEP(11)
            HSTEP(12) HSTEP(13) HSTEP(14) HSTEP(15)
            __syncthreads();                  // B1: hist complete

            if (t < NBIN) {
                u32 ssum = 0;
#pragma unroll
                for (int r2 = 0; r2 < NREP; ++r2)
                    ssum += hist[t * NREP + ((r2 + t) & (NREP - 1))];
                part[t] = ssum;
            }
            __syncthreads();                  // B2: part[] ready

            if (wid == 0) {
                u32 s8 = 0;
#pragma unroll
                for (int i = 0; i < 8; ++i)
                    s8 += part[lane * 8 + ((i + lane) & 7)];
                u32 cum = s8;
                for (int off = 1; off < 64; off <<= 1) {
                    const u32 o = __shfl_up(cum, off);
                    if (lane >= off) cum += o;
                }
                const u64 mm = __ballot(cum >= (u32)KP1);
                const int L  = __ffsll((unsigned long long)mm) - 1;
                const u32 below = __shfl(cum - s8, L);
                const u32 bc = (lane < 8) ? part[L * 8 + lane] : 0u;
                u32 ic = bc;
                for (int off = 1; off < 8; off <<= 1) {
                    const u32 o = __shfl_up(ic, off);
                    if (lane >= off) ic += o;
                }
                const u64 mm2 = __ballot(lane < 8 && (below + ic) >= (u32)KP1);
                const int l2  = __ffsll((unsigned long long)mm2) - 1;
                if (lane == 0) s_thr = (u32)(L * 8 + l2 + 1) << 22;
            } else {
                if (t == 64) cnt = 0u;        // reset for this seed's collect
                for (int i = t - 64; i < NBIN * NREP; i += 960) hist[i] = 0u;
            }
            __syncthreads();                  // B3: thr ready, hist zeroed, cnt=0

            // ---- collect candidates (recompute d: bitwise same as HSTEP) --
            const float thrf = __uint_as_float(s_thr);
#define CSTEP(i) { const float dx = px##i - cx, dy = py##i - cy, dz = pz##i - cz; \
        const float d = fmaf(dz, dz, fmaf(dy, dy, dx * dx)); \
        if (d < thrf) { const u32 sl = atomicAdd(&cnt, 1u); \
                        if (sl < (u32)CAP) cand[sl] = d; } }
            CSTEP(0)  CSTEP(1)  CSTEP(2)  CSTEP(3)
            CSTEP(4)  CSTEP(5)  CSTEP(6)  CSTEP(7)
            CSTEP(8)  CSTEP(9)  CSTEP(10) CSTEP(11)
            CSTEP(12) CSTEP(13) CSTEP(14) CSTEP(15)
            __syncthreads();                  // B4: candidates ready

            if (wid == 0) {
                const u32 n = min(cnt, (u32)CAP);
                for (u32 base = 0; base < n; base += 64) {
                    const u32 idx = base + (u32)lane;
                    const float vv = (idx < n) ? cand[idx] : 3.0e38f;
                    u32 r2 = 0;
                    for (u32 jj = 0; jj < n; ++jj) {
                        const float w = cand[jj];
                        r2 += (w < vv || (w == vv && jj < idx)) ? 1u : 0u;
                    }
                    if (idx < n && r2 < (u32)KP1)
                        topd[(b * N_SEEDS + s) * KP1 + r2] = sqrtf(vv);
                }
            }
        }

        // -------- signal completion (one fence per block, off hot path) ----
        __syncthreads();
        if (t == 0) {
            __threadfence();                  // make topd visible at agent scope
            __hip_atomic_fetch_add(done, 1, __ATOMIC_RELAXED,
                                   __HIP_MEMORY_SCOPE_AGENT);
        }

        // ================= stats role (block B only, single-pass) ==========
        if (bid == B) {
            const int target = NKNN * B - 1;      // done init = -1 (0xFF memset)
            if (t == 0) {
                while (__hip_atomic_load(done, __ATOMIC_RELAXED,
                                         __HIP_MEMORY_SCOPE_AGENT) != target)
                    __builtin_amdgcn_s_sleep(8);
            }
            __syncthreads();
            __threadfence();    // acquire side: invalidate before topd reads

            const int pairs = B * N_SEEDS;
            double* red = (double*)hist;          // 24 KB scratch, hist is dead

            // one pass: per-pair pairsum -> P, Q; first elem -> F (S1 = P-F)
            double P_ = 0.0, Q_ = 0.0, F_ = 0.0;
            for (int pr = t; pr < pairs; pr += 1024) {
                double ps = 0.0;
                for (int jj = 0; jj < KP1; ++jj)
                    ps += (double)topd[pr * KP1 + jj];
                P_ += ps;
                Q_ += ps * ps;
                F_ += (double)topd[pr * KP1];     // rank-0 (self) element
            }
            red[t*3+0] = P_; red[t*3+1] = Q_; red[t*3+2] = F_;
            __syncthreads();
            for (int off = 512; off; off >>= 1) {
                if (t < off) {
                    red[t*3+0] += red[(t+off)*3+0];
                    red[t*3+1] += red[(t+off)*3+1];
                    red[t*3+2] += red[(t+off)*3+2];
                }
                __syncthreads();
            }
            if (t == 0) {
                const double Pt = red[0], Qt = red[1], Ft = red[2];
                const double S1 = Pt - Ft;                       // sum of [:,:,1:]
                const double om = S1 / (double)(pairs * (KP1 - 1));
                const double d11 = om * (double)KP1;
                const double sm = Pt / d11;                      // sum of m
                const double sq = Qt / (d11 * d11);              // sum of m^2
                const double var = (sq - sm * sm / (double)pairs)
                                   / (double)(pairs - 1);
                out[0] = (float)var;
            }
        }
    }
}

// ---------------------------------------------------------------------------
extern "C" void kernel_launch(void* const* d_in, const int* in_sizes, int n_in,
                              void* d_out, int out_size, void* d_ws, size_t ws_size,
                              hipStream_t stream) {
    const float* pcs = (const float*)d_in[0];
    const int B = in_sizes[0] / (N_PTS * 3);

    int*   seeds = (int*)d_ws;                          // B*20 ints
    int*   done  = (int*)((char*)d_ws + 5120);          // 1 int, init -1
    float* topd  = (float*)((char*)d_ws + 8192);        // B*20*11 floats
    float* out   = (float*)d_out;

    // seeds -> -1, done -> -1 every launch (graph replays don't re-poison)
    (void)hipMemsetAsync(d_ws, 0xFF, 8192, stream);

    fused_kernel<<<B * (1 + NKNN), 1024, 0, stream>>>(pcs, seeds, done, topd, out, B);
}